// Round 13
// baseline (340.694 us; speedup 1.0000x reference)
//
#include <hip/hip_runtime.h>
#include <hip/hip_fp16.h>
#include <cstdint>

#define LATN 16
#define LONGN 12
#define PP 192          // LAT*LONG positions per n
#define CIN 128
#define CMID 128
#define EPSV 1e-5f
#define SPLIT 4         // scatter blocks per n (channel split)
#define CHB 32          // scatter channels per block
#define TST 36          // [p][c] tile stride (floats)
#define UMAXA 4         // scatter pipeline depth

typedef float v2f __attribute__((ext_vector_type(2)));
typedef float f32x4 __attribute__((ext_vector_type(4)));
typedef _Float16 half8 __attribute__((ext_vector_type(8)));

// ---------------- counting sort of scatter records by destination CELL (n,p) ----------------

__global__ void count2_kernel(const int* __restrict__ pidx, int* __restrict__ counts, int E) {
    int e = blockIdx.x * 256 + threadIdx.x;
    if (e >= E) return;
#pragma unroll
    for (int i = 0; i < 4; i++) {
        int v = pidx[i * E + e];
        atomicAdd(&counts[v], 1);
    }
}

__global__ void scan1_kernel(const int* __restrict__ cnt, int* __restrict__ startp,
                             int* __restrict__ bsum) {
    __shared__ int sd[1024];
    int t = threadIdx.x, b = blockIdx.x;
    int v = cnt[b * 1024 + t];
    sd[t] = v;
    __syncthreads();
    for (int off = 1; off < 1024; off <<= 1) {
        int x = (t >= off) ? sd[t - off] : 0;
        __syncthreads();
        sd[t] += x;
        __syncthreads();
    }
    startp[b * 1024 + t] = sd[t] - v;
    if (t == 1023) bsum[b] = sd[t];
}

__global__ void scan2_kernel(int* __restrict__ bsum, int* __restrict__ grand, int nb) {
    __shared__ int sd[1024];
    int t = threadIdx.x;
    int v = (t < nb) ? bsum[t] : 0;
    sd[t] = v;
    __syncthreads();
    for (int off = 1; off < 1024; off <<= 1) {
        int x = (t >= off) ? sd[t - off] : 0;
        __syncthreads();
        sd[t] += x;
        __syncthreads();
    }
    if (t < nb) bsum[t] = sd[t] - v;
    if (t == 1023) *grand = sd[1023];
}

__global__ void addback_kernel(int* __restrict__ startp, const int* __restrict__ bsum,
                               int* __restrict__ cur) {
    int v = blockIdx.x * 1024 + threadIdx.x;
    int s = startp[v] + bsum[blockIdx.x];
    startp[v] = s;
    cur[v] = s;
}

__global__ void record_kernel(const int* __restrict__ pidx, const int* __restrict__ src_idx,
                              const float* __restrict__ delta, int* __restrict__ cur,
                              uint2* __restrict__ rec, int E) {
    int e = blockIdx.x * 256 + threadIdx.x;
    if (e >= E) return;
    int src = src_idx[e];
#pragma unroll
    for (int i = 0; i < 4; i++) {
        int v = pidx[i * E + e];
        int p = v - (v / PP) * PP;
        int pos = atomicAdd(&cur[v], 1);
        rec[pos] = make_uint2((uint32_t)src | ((uint32_t)p << 18),
                              __float_as_uint(delta[i * E + e]));
    }
}

// weights -> f16x2 k-pairs, layout [i][kp][o] (fallback path)
__global__ void wt2_kernel(const float* __restrict__ w, uint32_t* __restrict__ wt2) {
    int id = blockIdx.x * 256 + threadIdx.x;
    if (id >= CIN * 6 * CMID) return;
    int o = id & 127;
    int kp = (id >> 7) % 6;
    int i = id / (128 * 6);
    float a = w[(o * 128 + i) * 12 + 2 * kp];
    float b = w[(o * 128 + i) * 12 + 2 * kp + 1];
    __half2 h = __floats2half2_rn(a, b);
    wt2[id] = *reinterpret_cast<uint32_t*>(&h);
}

// ---------------- W' prep: MFMA-A-fragment-ordered t-replicated weights ----------------

__global__ void wA_kernel(const float* __restrict__ w, _Float16* __restrict__ wA) {
    int id = blockIdx.x * 256 + threadIdx.x;
    if (id >= 16 * 6 * 48 * 64) return;
    int lane = id & 63;
    int rest = id >> 6;
    int s = rest % 48;
    int mt = (rest / 48) % 6;
    int g = rest / (48 * 6);
    int m = mt * 16 + (lane & 15);
    int o = m / 12;
    int t = m - o * 12;
    int og = g * 8 + o;
    _Float16 vals[8];
#pragma unroll
    for (int j = 0; j < 8; j++) {
        int kh = s * 32 + (lane >> 4) * 8 + j;
        int c = kh / PP;
        int p = kh - c * PP;
        int lat = p / LONGN;
        int ll = p - lat * LONGN;
        int k = (ll - t + 18) % 12;
        vals[j] = (_Float16)w[((og)*128 + c * 16 + lat) * 12 + k];
    }
    *(uint4*)(wA + (size_t)id * 8) = *(const uint4*)vals;
}

// ---------------- scatter v2: 16-lane records (float2), same-XCD split blocks ----------
// rotation: channels {2il, 2il+1} of position p live at chunk ((il + (p&15)) & 15)

__global__ __launch_bounds__(256, 5) void scatter_kernel(
    const float* __restrict__ x, const uint2* __restrict__ rec,
    const int* __restrict__ start2, _Float16* __restrict__ grid) {
    __shared__ __align__(16) float tile[PP * TST];
    __shared__ int s2c[PP + 1];

    const int raw = blockIdx.x;
    const int xcd = raw & 7;
    const int r2 = raw >> 3;
    const int n = (r2 >> 2) * 8 + xcd;   // all 4 split blocks of n share an XCD
    const int b = r2 & 3;
    const int tid = threadIdx.x;

    {
        float4 zz = {0.f, 0.f, 0.f, 0.f};
        float4* t4 = (float4*)tile;
        for (int idx = tid; idx < PP * TST / 4; idx += 256) t4[idx] = zz;
        for (int idx = tid; idx < PP + 1; idx += 256) s2c[idx] = start2[n * PP + idx];
    }
    __syncthreads();

    {
        const int il = tid & 15;             // lane within record: 2 channels
        const int slot = tid >> 4;           // 0..15, owns p in [slot*12, slot*12+12)
        const int cbase = b * CHB + il * 2;
        const int e1 = s2c[slot * 12 + 12];
        for (int e = s2c[slot * 12]; e < e1; e += UMAXA) {
            uint2 rv[UMAXA];
            float2 xv[UMAXA];
#pragma unroll
            for (int u = 0; u < UMAXA; u++) {
                if (e + u < e1) rv[u] = rec[e + u];
            }
#pragma unroll
            for (int u = 0; u < UMAXA; u++) {
                if (e + u < e1) {
                    int src = (int)(rv[u].x & 0x3FFFFu);
                    xv[u] = *(const float2*)(x + (size_t)src * CIN + cbase);
                }
            }
#pragma unroll
            for (int u = 0; u < UMAXA; u++) {
                if (e + u < e1) {
                    float dl = __uint_as_float(rv[u].y);
                    int p = (int)(rv[u].x >> 18);
                    float* tp = tile + p * TST + (((il + (p & 15)) & 15) << 1);
                    float2 t = *(const float2*)tp;
                    t.x += xv[u].x * dl;
                    t.y += xv[u].y * dl;
                    *(float2*)tp = t;
                }
            }
        }
    }
    __syncthreads();

    // writeout: tile -> f16 grid[n][c][p]; thread = (c = tid&31, pc = tid>>5)
    {
        const int c = tid & 31;
        const int pc = tid >> 5;
        const int gch = b * CHB + c;
        _Float16* gdst = grid + ((size_t)n * CIN + gch) * PP;
        const int il = c >> 1;
        const int cm = c & 1;
#pragma unroll
        for (int j16 = 0; j16 < 3; j16++) {
            int pbase = pc * 24 + j16 * 8;
            _Float16 hh[8];
#pragma unroll
            for (int i = 0; i < 8; i++) {
                int p = pbase + i;
                hh[i] = (_Float16)tile[p * TST + ((((il + (p & 15)) & 15) << 1) + cm)];
            }
            *(uint4*)(gdst + pbase) = *(const uint4*)hh;
        }
    }
}

// ---------------- GEMM v3: 64-n tile, 4 waves, explicit prefetch, B direct from global ----

__global__ __launch_bounds__(256, 5) void gemm_kernel(
    const _Float16* __restrict__ grid, const _Float16* __restrict__ wA,
    const float* __restrict__ conv_b, const float* __restrict__ gn_w,
    const float* __restrict__ gn_b, float* __restrict__ out) {
    __shared__ float Clds[96 * 66];                     // 25344 B

    const int bid = blockIdx.x;
    const int g = bid & 15;             // same-g blocks share XCD (bid%8 fixed) -> wA L2-hot
    const int ntile = bid >> 4;
    const int tid = threadIdx.x;
    const int lane = tid & 63;
    const int wv = tid >> 6;
    const int mh = wv & 1;              // m-half: m-tiles mh*3 .. mh*3+2
    const int nh = wv >> 1;             // n-half: cols nh*32 .. nh*32+31

    const int nn = lane & 15;
    const int h = lane >> 4;

    const _Float16* a0 = wA + ((size_t)(g * 6 + mh * 3) * 48) * 512 + lane * 8;
    const _Float16* a1 = a0 + (size_t)48 * 512;
    const _Float16* a2 = a1 + (size_t)48 * 512;
    const _Float16* b0 = grid + ((size_t)(ntile * 64 + nh * 32 + nn) * CIN + g * 8) * PP + h * 8;
    const _Float16* b1 = b0 + (size_t)16 * CIN * PP;

    f32x4 acc00 = {0.f, 0.f, 0.f, 0.f}, acc01 = {0.f, 0.f, 0.f, 0.f};
    f32x4 acc10 = {0.f, 0.f, 0.f, 0.f}, acc11 = {0.f, 0.f, 0.f, 0.f};
    f32x4 acc20 = {0.f, 0.f, 0.f, 0.f}, acc21 = {0.f, 0.f, 0.f, 0.f};

    half8 cA0 = *(const half8*)(a0);
    half8 cA1 = *(const half8*)(a1);
    half8 cA2 = *(const half8*)(a2);
    half8 cB0 = *(const half8*)(b0);
    half8 cB1 = *(const half8*)(b1);

#pragma unroll 4
    for (int s = 0; s < 48; s++) {
        half8 nA0 = cA0, nA1 = cA1, nA2 = cA2, nB0 = cB0, nB1 = cB1;
        if (s + 1 < 48) {
            nA0 = *(const half8*)(a0 + (size_t)(s + 1) * 512);
            nA1 = *(const half8*)(a1 + (size_t)(s + 1) * 512);
            nA2 = *(const half8*)(a2 + (size_t)(s + 1) * 512);
            nB0 = *(const half8*)(b0 + (size_t)(s + 1) * 32);
            nB1 = *(const half8*)(b1 + (size_t)(s + 1) * 32);
        }
        acc00 = __builtin_amdgcn_mfma_f32_16x16x32_f16(cA0, cB0, acc00, 0, 0, 0);
        acc10 = __builtin_amdgcn_mfma_f32_16x16x32_f16(cA1, cB0, acc10, 0, 0, 0);
        acc20 = __builtin_amdgcn_mfma_f32_16x16x32_f16(cA2, cB0, acc20, 0, 0, 0);
        acc01 = __builtin_amdgcn_mfma_f32_16x16x32_f16(cA0, cB1, acc01, 0, 0, 0);
        acc11 = __builtin_amdgcn_mfma_f32_16x16x32_f16(cA1, cB1, acc11, 0, 0, 0);
        acc21 = __builtin_amdgcn_mfma_f32_16x16x32_f16(cA2, cB1, acc21, 0, 0, 0);
        cA0 = nA0; cA1 = nA1; cA2 = nA2; cB0 = nB0; cB1 = nB1;
    }

    // ---- dump C to LDS [96 m][64 n] stride 66 ----
    {
        const int mbase = mh * 48 + h * 4;
        const int ncol = nh * 32 + nn;
#pragma unroll
        for (int j = 0; j < 4; j++) {
            Clds[(mbase + j) * 66 + ncol] = acc00[j];
            Clds[(mbase + j) * 66 + ncol + 16] = acc01[j];
            Clds[(mbase + 16 + j) * 66 + ncol] = acc10[j];
            Clds[(mbase + 16 + j) * 66 + ncol + 16] = acc11[j];
            Clds[(mbase + 32 + j) * 66 + ncol] = acc20[j];
            Clds[(mbase + 32 + j) * 66 + ncol + 16] = acc21[j];
        }
    }
    __syncthreads();

    // ---- epilogue: silu + pool + groupnorm; thread = (nl = tid>>3, o = tid&7), 2 passes ----
    {
        const int o = tid & 7;
        const int oc = g * 8 + o;
        const float bias = conv_b[oc];
        const float gw = gn_w[oc], gb = gn_b[oc];
#pragma unroll
        for (int pp = 0; pp < 2; pp++) {
            const int nl = (tid >> 3) + pp * 32;
            float sv = 0.f;
#pragma unroll
            for (int t = 0; t < 12; t++) {
                float z = Clds[(o * 12 + t) * 66 + nl] + bias;
                sv += z / (1.f + __expf(-z));
            }
            sv *= (1.f / 12.f);
            float s1 = sv, s2 = sv * sv;
#pragma unroll
            for (int m = 1; m < 8; m <<= 1) {
                s1 += __shfl_xor(s1, m);
                s2 += __shfl_xor(s2, m);
            }
            float mu = s1 * 0.125f;
            float var = fmaxf(s2 * 0.125f - mu * mu, 0.f);
            float inv = rsqrtf(var + EPSV);
            out[(size_t)(ntile * 64 + nl) * CMID + oc] = (sv - mu) * inv * gw + gb;
        }
    }
}

// ---------------- fallback: r9 fused kernel (ws too small) ----------------

__global__ __launch_bounds__(256, 5) void fused_kernel(
    const float* __restrict__ x, const uint2* __restrict__ rec,
    const int* __restrict__ start2, const uint32_t* __restrict__ wt2,
    const float* __restrict__ conv_b, const float* __restrict__ gn_w,
    const float* __restrict__ gn_b, float* __restrict__ out) {
    __shared__ __align__(16) float tile[PP * TST];
    __shared__ int s2c[PP + 1];

    const int bid = blockIdx.x;
    const int n = bid >> 2;
    const int b = bid & 3;
    const int tid = threadIdx.x;

    {
        float4 zz = {0.f, 0.f, 0.f, 0.f};
        float4* t4 = (float4*)tile;
        for (int idx = tid; idx < PP * TST / 4; idx += 256) t4[idx] = zz;
        for (int idx = tid; idx < PP + 1; idx += 256) s2c[idx] = start2[n * PP + idx];
    }
    __syncthreads();

    {
        const int il = tid & 7;
        const int slot = tid >> 3;
        const int cbase = b * CHB + il * 4;
        const int e1 = s2c[slot * 6 + 6];
        float* tbase = tile + il * 4;
        for (int e = s2c[slot * 6]; e < e1; e += UMAXA) {
            uint2 rv[UMAXA];
            float4 xv[UMAXA];
#pragma unroll
            for (int u = 0; u < UMAXA; u++) {
                if (e + u < e1) rv[u] = rec[e + u];
            }
#pragma unroll
            for (int u = 0; u < UMAXA; u++) {
                if (e + u < e1) {
                    int src = (int)(rv[u].x & 0x3FFFFu);
                    xv[u] = *(const float4*)(x + (size_t)src * CIN + cbase);
                }
            }
#pragma unroll
            for (int u = 0; u < UMAXA; u++) {
                if (e + u < e1) {
                    float dl = __uint_as_float(rv[u].y);
                    int p = (int)(rv[u].x >> 18);
                    float* tp = tbase + p * TST;
                    float4 t = *(const float4*)tp;
                    t.x += xv[u].x * dl;
                    t.y += xv[u].y * dl;
                    t.z += xv[u].z * dl;
                    t.w += xv[u].w * dl;
                    *(float4*)tp = t;
                }
            }
        }
    }
    __syncthreads();

    const int o_local = tid & 31;
    const int q = tid >> 5;
    const int g_local = o_local >> 3;
    const int o = b * CHB + o_local;
    const int ch = g_local * 8 + q;

    v2f acc2[6];
#pragma unroll
    for (int u = 0; u < 6; u++) acc2[u] = (v2f)(0.f);

    const uint32_t* wcol = wt2 + (size_t)(q * LATN) * 6 * CMID + o;

#pragma unroll
    for (int lat = 0; lat < LATN; lat++) {
        float r[12];
#pragma unroll
        for (int j = 0; j < 12; j++)
            r[j] = tile[(lat * LONGN + j) * TST + ch];
        v2f rp[12];
#pragma unroll
        for (int j = 0; j < 12; j++) {
            rp[j].x = r[(j + 6) % 12];
            rp[j].y = r[(j + 7) % 12];
        }
        const uint32_t* wrow = wcol + (size_t)(lat * 6) * CMID;
#pragma unroll
        for (int kp = 0; kp < 6; kp++) {
            uint32_t wp = wrow[kp * CMID];
            __half2 h2 = *reinterpret_cast<__half2*>(&wp);
            float wlo = __half2float(h2.x);
            float whi = __half2float(h2.y);
            v2f wl2 = {wlo, wlo}, wh2 = {whi, whi};
#pragma unroll
            for (int u = 0; u < 6; u++) {
                acc2[u] += wl2 * rp[(2 * kp + 2 * u) % 12];
                acc2[u] += wh2 * rp[(2 * kp + 2 * u + 1) % 12];
            }
        }
    }
    __syncthreads();

    float* pbuf = tile;
#pragma unroll
    for (int u = 0; u < 6; u++) {
        pbuf[(q * 12 + 2 * u) * 32 + o_local] = acc2[u].x;
        pbuf[(q * 12 + 2 * u + 1) * 32 + o_local] = acc2[u].y;
    }
    __syncthreads();

    float* gbuf = tile + 8 * 12 * 32;
    float sv = 0.f;
    if (tid < 32) {
        float bias = conv_b[b * CHB + tid];
#pragma unroll
        for (int t = 0; t < 12; t++) {
            float z = bias;
#pragma unroll
            for (int qq = 0; qq < 8; qq++) z += pbuf[(qq * 12 + t) * 32 + tid];
            sv += z / (1.f + __expf(-z));
        }
        sv *= (1.f / 12.f);
        gbuf[tid] = sv;
    }
    __syncthreads();
    if (tid < 32) {
        int gb = tid & ~7;
        float mu = 0.f, m2 = 0.f;
#pragma unroll
        for (int j = 0; j < 8; j++) {
            float v = gbuf[gb + j];
            mu += v;
            m2 += v * v;
        }
        mu *= 0.125f;
        float var = m2 * 0.125f - mu * mu;
        var = fmaxf(var, 0.f);
        float inv = rsqrtf(var + EPSV);
        int oc = b * CHB + tid;
        out[(size_t)n * CMID + oc] = (sv - mu) * inv * gn_w[oc] + gn_b[oc];
    }
}

extern "C" void kernel_launch(void* const* d_in, const int* in_sizes, int n_in,
                              void* d_out, int out_size, void* d_ws, size_t ws_size,
                              hipStream_t stream) {
    const float* x = (const float*)d_in[0];
    const int* pidx = (const int*)d_in[2];
    const float* delta = (const float*)d_in[3];
    const int* src_idx = (const int*)d_in[4];
    const float* conv_w = (const float*)d_in[5];
    const float* conv_b = (const float*)d_in[6];
    const float* gn_w = (const float*)d_in[7];
    const float* gn_b = (const float*)d_in[8];
    float* out = (float*)d_out;

    int E = in_sizes[0] / CIN;          // 200000
    int N = out_size / CMID;            // 4096
    int ncells = N * PP;                // 786432

    char* ws = (char*)d_ws;
    size_t off = 0;
    auto alloc = [&](size_t bytes) {
        size_t cur = off;
        off = (off + bytes + 255) & ~(size_t)255;
        return cur;
    };
    int* count2 = (int*)(ws + alloc((size_t)ncells * 4));   // reused as cur2 after scan1
    int* start2 = (int*)(ws + alloc((size_t)(ncells + 1) * 4));
    int* bsum   = (int*)(ws + alloc((size_t)1024 * 4));
    uint2* rec  = (uint2*)(ws + alloc((size_t)4 * E * 8));
    uint32_t* wt2 = (uint32_t*)(ws + alloc((size_t)CIN * 6 * CMID * 4));
    size_t wA_off = alloc((size_t)16 * 6 * 48 * 64 * 8 * 2);
    size_t grid_off = alloc((size_t)N * CIN * PP * 2);
    _Float16* wA = (_Float16*)(ws + wA_off);
    _Float16* gridbuf = (_Float16*)(ws + grid_off);
    bool two_pass = (off <= ws_size);

    hipMemsetAsync(count2, 0, (size_t)ncells * 4, stream);

    int gE = (E + 255) / 256;
    int nb = ncells / 1024;             // 768
    count2_kernel<<<gE, 256, 0, stream>>>(pidx, count2, E);
    scan1_kernel<<<nb, 1024, 0, stream>>>(count2, start2, bsum);
    scan2_kernel<<<1, 1024, 0, stream>>>(bsum, start2 + ncells, nb);
    addback_kernel<<<nb, 1024, 0, stream>>>(start2, bsum, count2);
    record_kernel<<<gE, 256, 0, stream>>>(pidx, src_idx, delta, count2, rec, E);

    if (two_pass) {
        wA_kernel<<<(16 * 6 * 48 * 64 + 255) / 256, 256, 0, stream>>>(conv_w, wA);
        scatter_kernel<<<N * SPLIT, 256, 0, stream>>>(x, rec, start2, gridbuf);
        gemm_kernel<<<16 * 64, 256, 0, stream>>>(gridbuf, wA, conv_b, gn_w, gn_b, out);
    } else {
        wt2_kernel<<<(CIN * 6 * CMID + 255) / 256, 256, 0, stream>>>(conv_w, wt2);
        fused_kernel<<<N * SPLIT, 256, 0, stream>>>(x, rec, start2, wt2, conv_b, gn_w, gn_b, out);
    }
}

// Round 14
// 289.236 us; speedup vs baseline: 1.1779x; 1.1779x over previous
//
#include <hip/hip_runtime.h>
#include <hip/hip_fp16.h>
#include <cstdint>

#define LATN 16
#define LONGN 12
#define PP 192          // LAT*LONG positions per n
#define CIN 128
#define CMID 128
#define EPSV 1e-5f
#define SPLIT 4         // scatter blocks per n (channel split)
#define CHB 32          // scatter channels per block
#define TST 36          // [p][c] tile stride (floats)
#define UMAXA 4         // scatter pipeline depth
#define SPN 32          // slots per n (each owns 6 p's)

typedef float v2f __attribute__((ext_vector_type(2)));
typedef float f32x4 __attribute__((ext_vector_type(4)));
typedef _Float16 half8 __attribute__((ext_vector_type(8)));

// ---------------- counting sort of scatter records by SLOT (n, p/6), padded to x4 ----------

// also null-fills the padded rec buffer: {p=192 scratch row, delta=0}
__global__ void count2_kernel(const int* __restrict__ pidx, int* __restrict__ counts,
                              uint2* __restrict__ rec, int E, int padtot, int nthreads) {
    int gid = blockIdx.x * 256 + threadIdx.x;
    uint2 nullrec = make_uint2((uint32_t)PP << 18, 0u);
    for (int j = gid; j < padtot; j += nthreads) rec[j] = nullrec;
    if (gid >= E) return;
#pragma unroll
    for (int i = 0; i < 4; i++) {
        int v = pidx[i * E + gid];
        int n = v / PP;
        int p = v - n * PP;
        atomicAdd(&counts[n * SPN + p / 6], 1);
    }
}

// scan of ROUNDED-UP counts (multiple of UMAXA); 128 blocks x 1024
__global__ void scan1_kernel(const int* __restrict__ cnt, int* __restrict__ startp,
                             int* __restrict__ bsum) {
    __shared__ int sd[1024];
    int t = threadIdx.x, b = blockIdx.x;
    int v = (cnt[b * 1024 + t] + 3) & ~3;
    sd[t] = v;
    __syncthreads();
    for (int off = 1; off < 1024; off <<= 1) {
        int x = (t >= off) ? sd[t - off] : 0;
        __syncthreads();
        sd[t] += x;
        __syncthreads();
    }
    startp[b * 1024 + t] = sd[t] - v;
    if (t == 1023) bsum[b] = sd[t];
}

__global__ void scan2_kernel(int* __restrict__ bsum, int* __restrict__ grand, int nb) {
    __shared__ int sd[1024];
    int t = threadIdx.x;
    int v = (t < nb) ? bsum[t] : 0;
    sd[t] = v;
    __syncthreads();
    for (int off = 1; off < 1024; off <<= 1) {
        int x = (t >= off) ? sd[t - off] : 0;
        __syncthreads();
        sd[t] += x;
        __syncthreads();
    }
    if (t < nb) bsum[t] = sd[t] - v;
    if (t == 1023) *grand = sd[1023];
}

__global__ void addback_kernel(int* __restrict__ startp, const int* __restrict__ bsum,
                               int* __restrict__ cur) {
    int v = blockIdx.x * 1024 + threadIdx.x;
    int s = startp[v] + bsum[blockIdx.x];
    startp[v] = s;
    cur[v] = s;
}

// emit slot-bucketed records: rec.x = src | (p<<18), rec.y = delta bits
__global__ void record_kernel(const int* __restrict__ pidx, const int* __restrict__ src_idx,
                              const float* __restrict__ delta, int* __restrict__ cur,
                              uint2* __restrict__ rec, int E) {
    int e = blockIdx.x * 256 + threadIdx.x;
    if (e >= E) return;
    int src = src_idx[e];
#pragma unroll
    for (int i = 0; i < 4; i++) {
        int v = pidx[i * E + e];
        int n = v / PP;
        int p = v - n * PP;
        int pos = atomicAdd(&cur[n * SPN + p / 6], 1);
        rec[pos] = make_uint2((uint32_t)src | ((uint32_t)p << 18),
                              __float_as_uint(delta[i * E + e]));
    }
}

// weights -> f16x2 k-pairs, layout [i][kp][o] (fallback path)
__global__ void wt2_kernel(const float* __restrict__ w, uint32_t* __restrict__ wt2) {
    int id = blockIdx.x * 256 + threadIdx.x;
    if (id >= CIN * 6 * CMID) return;
    int o = id & 127;
    int kp = (id >> 7) % 6;
    int i = id / (128 * 6);
    float a = w[(o * 128 + i) * 12 + 2 * kp];
    float b = w[(o * 128 + i) * 12 + 2 * kp + 1];
    __half2 h = __floats2half2_rn(a, b);
    wt2[id] = *reinterpret_cast<uint32_t*>(&h);
}

// ---------------- W' prep: MFMA-A-fragment-ordered t-replicated weights ----------------

__global__ void wA_kernel(const float* __restrict__ w, _Float16* __restrict__ wA) {
    int id = blockIdx.x * 256 + threadIdx.x;
    if (id >= 16 * 6 * 48 * 64) return;
    int lane = id & 63;
    int rest = id >> 6;
    int s = rest % 48;
    int mt = (rest / 48) % 6;
    int g = rest / (48 * 6);
    int m = mt * 16 + (lane & 15);
    int o = m / 12;
    int t = m - o * 12;
    int og = g * 8 + o;
    _Float16 vals[8];
#pragma unroll
    for (int j = 0; j < 8; j++) {
        int kh = s * 32 + (lane >> 4) * 8 + j;
        int c = kh / PP;
        int p = kh - c * PP;
        int lat = p / LONGN;
        int ll = p - lat * LONGN;
        int k = (ll - t + 18) % 12;
        vals[j] = (_Float16)w[((og)*128 + c * 16 + lat) * 12 + k];
    }
    *(uint4*)(wA + (size_t)id * 8) = *(const uint4*)vals;
}

// ---------------- scatter v3: r12 body, unconditional 4-deep pipeline (padded slots) ------
// rotation: channels il*4..il*4+3 of position p live at chunk ((il + (p&7)) & 7)
// row 192 = scratch row for null/pad records.

__global__ __launch_bounds__(256, 5) void scatter_kernel(
    const float* __restrict__ x, const uint2* __restrict__ rec,
    const int* __restrict__ start2, _Float16* __restrict__ grid) {
    __shared__ __align__(16) float tile[(PP + 1) * TST];
    __shared__ int sst[SPN + 1];

    const int bid = blockIdx.x;
    const int n = bid >> 2;
    const int b = bid & 3;
    const int tid = threadIdx.x;

    {
        float4 zz = {0.f, 0.f, 0.f, 0.f};
        float4* t4 = (float4*)tile;
        for (int idx = tid; idx < (PP + 1) * TST / 4; idx += 256) t4[idx] = zz;
        if (tid < SPN + 1) sst[tid] = start2[n * SPN + tid];
    }
    __syncthreads();

    {
        const int il = tid & 7;
        const int slot = tid >> 3;
        const int cbase = b * CHB + il * 4;
        const int e0 = sst[slot];
        const int e1 = sst[slot + 1];          // (e1-e0) % 4 == 0 guaranteed
        for (int e = e0; e < e1; e += UMAXA) {
            uint2 rv[UMAXA];
            float4 xv[UMAXA];
#pragma unroll
            for (int u = 0; u < UMAXA; u++) rv[u] = rec[e + u];
#pragma unroll
            for (int u = 0; u < UMAXA; u++) {
                int src = (int)(rv[u].x & 0x3FFFFu);
                xv[u] = *(const float4*)(x + (size_t)src * CIN + cbase);
            }
#pragma unroll
            for (int u = 0; u < UMAXA; u++) {
                float dl = __uint_as_float(rv[u].y);
                int p = (int)(rv[u].x >> 18);
                float* tp = tile + p * TST + (((il + (p & 7)) & 7) << 2);
                float4 t = *(const float4*)tp;
                t.x += xv[u].x * dl;
                t.y += xv[u].y * dl;
                t.z += xv[u].z * dl;
                t.w += xv[u].w * dl;
                *(float4*)tp = t;
            }
        }
    }
    __syncthreads();

    // writeout: tile -> f16 grid[n][c][p]; thread = (c = tid&31, pc = tid>>5)
    {
        const int c = tid & 31;
        const int pc = tid >> 5;
        const int gch = b * CHB + c;
        _Float16* gdst = grid + ((size_t)n * CIN + gch) * PP;
        const int il = c >> 2;
        const int cm = c & 3;
#pragma unroll
        for (int j16 = 0; j16 < 3; j16++) {
            int pbase = pc * 24 + j16 * 8;
            _Float16 hh[8];
#pragma unroll
            for (int i = 0; i < 8; i++) {
                int p = pbase + i;
                hh[i] = (_Float16)tile[p * TST + ((((il + (p & 7)) & 7) << 2) + cm)];
            }
            *(uint4*)(gdst + pbase) = *(const uint4*)hh;
        }
    }
}

// ---------------- GEMM v3 (unchanged from r12): 64-n tile, 4 waves, 1-deep prefetch ------

__global__ __launch_bounds__(256, 5) void gemm_kernel(
    const _Float16* __restrict__ grid, const _Float16* __restrict__ wA,
    const float* __restrict__ conv_b, const float* __restrict__ gn_w,
    const float* __restrict__ gn_b, float* __restrict__ out) {
    __shared__ float Clds[96 * 66];                     // 25344 B

    const int bid = blockIdx.x;
    const int g = bid & 15;
    const int ntile = bid >> 4;
    const int tid = threadIdx.x;
    const int lane = tid & 63;
    const int wv = tid >> 6;
    const int mh = wv & 1;
    const int nh = wv >> 1;

    const int nn = lane & 15;
    const int h = lane >> 4;

    const _Float16* a0 = wA + ((size_t)(g * 6 + mh * 3) * 48) * 512 + lane * 8;
    const _Float16* a1 = a0 + (size_t)48 * 512;
    const _Float16* a2 = a1 + (size_t)48 * 512;
    const _Float16* b0 = grid + ((size_t)(ntile * 64 + nh * 32 + nn) * CIN + g * 8) * PP + h * 8;
    const _Float16* b1 = b0 + (size_t)16 * CIN * PP;

    f32x4 acc00 = {0.f, 0.f, 0.f, 0.f}, acc01 = {0.f, 0.f, 0.f, 0.f};
    f32x4 acc10 = {0.f, 0.f, 0.f, 0.f}, acc11 = {0.f, 0.f, 0.f, 0.f};
    f32x4 acc20 = {0.f, 0.f, 0.f, 0.f}, acc21 = {0.f, 0.f, 0.f, 0.f};

    half8 cA0 = *(const half8*)(a0);
    half8 cA1 = *(const half8*)(a1);
    half8 cA2 = *(const half8*)(a2);
    half8 cB0 = *(const half8*)(b0);
    half8 cB1 = *(const half8*)(b1);

#pragma unroll 4
    for (int s = 0; s < 48; s++) {
        half8 nA0 = cA0, nA1 = cA1, nA2 = cA2, nB0 = cB0, nB1 = cB1;
        if (s + 1 < 48) {
            nA0 = *(const half8*)(a0 + (size_t)(s + 1) * 512);
            nA1 = *(const half8*)(a1 + (size_t)(s + 1) * 512);
            nA2 = *(const half8*)(a2 + (size_t)(s + 1) * 512);
            nB0 = *(const half8*)(b0 + (size_t)(s + 1) * 32);
            nB1 = *(const half8*)(b1 + (size_t)(s + 1) * 32);
        }
        acc00 = __builtin_amdgcn_mfma_f32_16x16x32_f16(cA0, cB0, acc00, 0, 0, 0);
        acc10 = __builtin_amdgcn_mfma_f32_16x16x32_f16(cA1, cB0, acc10, 0, 0, 0);
        acc20 = __builtin_amdgcn_mfma_f32_16x16x32_f16(cA2, cB0, acc20, 0, 0, 0);
        acc01 = __builtin_amdgcn_mfma_f32_16x16x32_f16(cA0, cB1, acc01, 0, 0, 0);
        acc11 = __builtin_amdgcn_mfma_f32_16x16x32_f16(cA1, cB1, acc11, 0, 0, 0);
        acc21 = __builtin_amdgcn_mfma_f32_16x16x32_f16(cA2, cB1, acc21, 0, 0, 0);
        cA0 = nA0; cA1 = nA1; cA2 = nA2; cB0 = nB0; cB1 = nB1;
    }

    {
        const int mbase = mh * 48 + h * 4;
        const int ncol = nh * 32 + nn;
#pragma unroll
        for (int j = 0; j < 4; j++) {
            Clds[(mbase + j) * 66 + ncol] = acc00[j];
            Clds[(mbase + j) * 66 + ncol + 16] = acc01[j];
            Clds[(mbase + 16 + j) * 66 + ncol] = acc10[j];
            Clds[(mbase + 16 + j) * 66 + ncol + 16] = acc11[j];
            Clds[(mbase + 32 + j) * 66 + ncol] = acc20[j];
            Clds[(mbase + 32 + j) * 66 + ncol + 16] = acc21[j];
        }
    }
    __syncthreads();

    {
        const int o = tid & 7;
        const int oc = g * 8 + o;
        const float bias = conv_b[oc];
        const float gw = gn_w[oc], gb = gn_b[oc];
#pragma unroll
        for (int pp = 0; pp < 2; pp++) {
            const int nl = (tid >> 3) + pp * 32;
            float sv = 0.f;
#pragma unroll
            for (int t = 0; t < 12; t++) {
                float z = Clds[(o * 12 + t) * 66 + nl] + bias;
                sv += z / (1.f + __expf(-z));
            }
            sv *= (1.f / 12.f);
            float s1 = sv, s2 = sv * sv;
#pragma unroll
            for (int m = 1; m < 8; m <<= 1) {
                s1 += __shfl_xor(s1, m);
                s2 += __shfl_xor(s2, m);
            }
            float mu = s1 * 0.125f;
            float var = fmaxf(s2 * 0.125f - mu * mu, 0.f);
            float inv = rsqrtf(var + EPSV);
            out[(size_t)(ntile * 64 + nl) * CMID + oc] = (sv - mu) * inv * gw + gb;
        }
    }
}

// ---------------- fallback: fused kernel (ws too small), slot-sorted records --------------

__global__ __launch_bounds__(256, 5) void fused_kernel(
    const float* __restrict__ x, const uint2* __restrict__ rec,
    const int* __restrict__ start2, const uint32_t* __restrict__ wt2,
    const float* __restrict__ conv_b, const float* __restrict__ gn_w,
    const float* __restrict__ gn_b, float* __restrict__ out) {
    __shared__ __align__(16) float tile[(PP + 1) * TST];
    __shared__ int sst[SPN + 1];

    const int bid = blockIdx.x;
    const int n = bid >> 2;
    const int b = bid & 3;
    const int tid = threadIdx.x;

    {
        float4 zz = {0.f, 0.f, 0.f, 0.f};
        float4* t4 = (float4*)tile;
        for (int idx = tid; idx < (PP + 1) * TST / 4; idx += 256) t4[idx] = zz;
        if (tid < SPN + 1) sst[tid] = start2[n * SPN + tid];
    }
    __syncthreads();

    {
        const int il = tid & 7;
        const int slot = tid >> 3;
        const int cbase = b * CHB + il * 4;
        const int e0 = sst[slot];
        const int e1 = sst[slot + 1];
        float* tbase = tile + il * 4;
        for (int e = e0; e < e1; e += UMAXA) {
            uint2 rv[UMAXA];
            float4 xv[UMAXA];
#pragma unroll
            for (int u = 0; u < UMAXA; u++) rv[u] = rec[e + u];
#pragma unroll
            for (int u = 0; u < UMAXA; u++) {
                int src = (int)(rv[u].x & 0x3FFFFu);
                xv[u] = *(const float4*)(x + (size_t)src * CIN + cbase);
            }
#pragma unroll
            for (int u = 0; u < UMAXA; u++) {
                float dl = __uint_as_float(rv[u].y);
                int p = (int)(rv[u].x >> 18);
                float* tp = tbase + p * TST;
                float4 t = *(const float4*)tp;
                t.x += xv[u].x * dl;
                t.y += xv[u].y * dl;
                t.z += xv[u].z * dl;
                t.w += xv[u].w * dl;
                *(float4*)tp = t;
            }
        }
    }
    __syncthreads();

    const int o_local = tid & 31;
    const int q = tid >> 5;
    const int g_local = o_local >> 3;
    const int o = b * CHB + o_local;
    const int ch = g_local * 8 + q;

    v2f acc2[6];
#pragma unroll
    for (int u = 0; u < 6; u++) acc2[u] = (v2f)(0.f);

    const uint32_t* wcol = wt2 + (size_t)(q * LATN) * 6 * CMID + o;

#pragma unroll
    for (int lat = 0; lat < LATN; lat++) {
        float r[12];
#pragma unroll
        for (int j = 0; j < 12; j++)
            r[j] = tile[(lat * LONGN + j) * TST + ch];
        v2f rp[12];
#pragma unroll
        for (int j = 0; j < 12; j++) {
            rp[j].x = r[(j + 6) % 12];
            rp[j].y = r[(j + 7) % 12];
        }
        const uint32_t* wrow = wcol + (size_t)(lat * 6) * CMID;
#pragma unroll
        for (int kp = 0; kp < 6; kp++) {
            uint32_t wp = wrow[kp * CMID];
            __half2 h2 = *reinterpret_cast<__half2*>(&wp);
            float wlo = __half2float(h2.x);
            float whi = __half2float(h2.y);
            v2f wl2 = {wlo, wlo}, wh2 = {whi, whi};
#pragma unroll
            for (int u = 0; u < 6; u++) {
                acc2[u] += wl2 * rp[(2 * kp + 2 * u) % 12];
                acc2[u] += wh2 * rp[(2 * kp + 2 * u + 1) % 12];
            }
        }
    }
    __syncthreads();

    float* pbuf = tile;
#pragma unroll
    for (int u = 0; u < 6; u++) {
        pbuf[(q * 12 + 2 * u) * 32 + o_local] = acc2[u].x;
        pbuf[(q * 12 + 2 * u + 1) * 32 + o_local] = acc2[u].y;
    }
    __syncthreads();

    float* gbuf = tile + 8 * 12 * 32;
    float sv = 0.f;
    if (tid < 32) {
        float bias = conv_b[b * CHB + tid];
#pragma unroll
        for (int t = 0; t < 12; t++) {
            float z = bias;
#pragma unroll
            for (int qq = 0; qq < 8; qq++) z += pbuf[(qq * 12 + t) * 32 + tid];
            sv += z / (1.f + __expf(-z));
        }
        sv *= (1.f / 12.f);
        gbuf[tid] = sv;
    }
    __syncthreads();
    if (tid < 32) {
        int gb = tid & ~7;
        float mu = 0.f, m2 = 0.f;
#pragma unroll
        for (int j = 0; j < 8; j++) {
            float v = gbuf[gb + j];
            mu += v;
            m2 += v * v;
        }
        mu *= 0.125f;
        float var = m2 * 0.125f - mu * mu;
        var = fmaxf(var, 0.f);
        float inv = rsqrtf(var + EPSV);
        int oc = b * CHB + tid;
        out[(size_t)n * CMID + oc] = (sv - mu) * inv * gn_w[oc] + gn_b[oc];
    }
}

extern "C" void kernel_launch(void* const* d_in, const int* in_sizes, int n_in,
                              void* d_out, int out_size, void* d_ws, size_t ws_size,
                              hipStream_t stream) {
    const float* x = (const float*)d_in[0];
    const int* pidx = (const int*)d_in[2];
    const float* delta = (const float*)d_in[3];
    const int* src_idx = (const int*)d_in[4];
    const float* conv_w = (const float*)d_in[5];
    const float* conv_b = (const float*)d_in[6];
    const float* gn_w = (const float*)d_in[7];
    const float* gn_b = (const float*)d_in[8];
    float* out = (float*)d_out;

    int E = in_sizes[0] / CIN;          // 200000
    int N = out_size / CMID;            // 4096
    int nslots = N * SPN;               // 131072
    int padtot = 4 * E + nslots * 3;    // max padded record count

    char* ws = (char*)d_ws;
    size_t off = 0;
    auto alloc = [&](size_t bytes) {
        size_t cur = off;
        off = (off + bytes + 255) & ~(size_t)255;
        return cur;
    };
    int* count2 = (int*)(ws + alloc((size_t)nslots * 4));   // reused as cur after scan
    int* start2 = (int*)(ws + alloc((size_t)(nslots + 1) * 4));
    int* bsum   = (int*)(ws + alloc((size_t)1024 * 4));
    uint2* rec  = (uint2*)(ws + alloc((size_t)padtot * 8));
    uint32_t* wt2 = (uint32_t*)(ws + alloc((size_t)CIN * 6 * CMID * 4));
    size_t wA_off = alloc((size_t)16 * 6 * 48 * 64 * 8 * 2);
    size_t grid_off = alloc((size_t)N * CIN * PP * 2);
    _Float16* wA = (_Float16*)(ws + wA_off);
    _Float16* gridbuf = (_Float16*)(ws + grid_off);
    bool two_pass = (off <= ws_size);

    hipMemsetAsync(count2, 0, (size_t)nslots * 4, stream);

    int gE = (E + 255) / 256;
    int nb = nslots / 1024;             // 128
    count2_kernel<<<gE, 256, 0, stream>>>(pidx, count2, rec, E, padtot, gE * 256);
    scan1_kernel<<<nb, 1024, 0, stream>>>(count2, start2, bsum);
    scan2_kernel<<<1, 1024, 0, stream>>>(bsum, start2 + nslots, nb);
    addback_kernel<<<nb, 1024, 0, stream>>>(start2, bsum, count2);
    record_kernel<<<gE, 256, 0, stream>>>(pidx, src_idx, delta, count2, rec, E);

    if (two_pass) {
        wA_kernel<<<(16 * 6 * 48 * 64 + 255) / 256, 256, 0, stream>>>(conv_w, wA);
        scatter_kernel<<<N * SPLIT, 256, 0, stream>>>(x, rec, start2, gridbuf);
        gemm_kernel<<<16 * 64, 256, 0, stream>>>(gridbuf, wA, conv_b, gn_w, gn_b, out);
    } else {
        wt2_kernel<<<(CIN * 6 * CMID + 255) / 256, 256, 0, stream>>>(conv_w, wt2);
        fused_kernel<<<N * SPLIT, 256, 0, stream>>>(x, rec, start2, wt2, conv_b, gn_w, gn_b, out);
    }
}